// Round 6
// baseline (3512.726 us; speedup 1.0000x reference)
//
#include <hip/hip_runtime.h>
#include <cstdint>
#include <cstddef>

// Problem constants
#define HN 304      // hidden size
#define G3 912      // 3*HN gate rows
#define US 76       // hidden units per slice (HN/4)
#define RS 228      // rows per slice (3*US)
#define NB 64       // batch
#define TSTEPS 1024 // encoder steps
#define LDEC 127    // decoder steps actually needed (L-1)
#define DCLS 128    // vocab / classes

// Output layout (floats): [softmax_cal 8128*128][target_cal 8128][asr_outputs 8128]
#define OUT_O1 1040384
#define OUT_O2 1048512

// Workspace layout (bytes). Proven available: ws_size >= 239,702,784 (R1-R5 ran).
static const size_t OFF_GI   = 0;             // 64*1024*912 f32 = 239,075,328
static const size_t OFF_HP   = 239075328ull;  // tagged h ping-pong: 2*64*304 u32 = 155,648
static const size_t OFF_AM   = 239230976ull;  // argmax tagged: 64*4 ull = 2,048
static const size_t OFF_ABRT = 239233024ull;  // 256
static const size_t OFF_TAB  = 239233280ull;  // 128*912 f32 = 466,944
static const size_t WS_NEED  = 239700224ull;  // <= proven bound

// ---------------------------------------------------------------------------
// Phase 1: gi[b,t,:] = x[b,t,:] @ enc_Wih^T + enc_bih   (M=65536, N=912, K=304)
// Reg-double-buffered global loads: tile k0+16 fetched during tile k0's MACs.
// FP32 accumulation order identical to R5 (k-ascending).
// ---------------------------------------------------------------------------
__global__ __launch_bounds__(256) void gi_gemm(const float* __restrict__ X,
                                               const float* __restrict__ W,
                                               const float* __restrict__ bias,
                                               float* __restrict__ out)
{
    __shared__ float xs[16][68];
    __shared__ float wsm[16][68];
    const int tid = threadIdx.x;
    const int m0 = blockIdx.x * 64;
    const int n0 = blockIdx.y * 64;
    const int tx = tid & 15, ty = tid >> 4;
    const int lr = tid >> 2;
    const int lk = (tid & 3) * 4;
    float c[4][4];
#pragma unroll
    for (int i = 0; i < 4; ++i)
#pragma unroll
        for (int j = 0; j < 4; ++j) c[i][j] = 0.f;

    const bool wok = (n0 + lr < G3);
    float4 xv = *(const float4*)(X + (size_t)(m0 + lr) * HN + lk);
    float4 wv = wok ? *(const float4*)(W + (size_t)(n0 + lr) * HN + lk)
                    : make_float4(0.f, 0.f, 0.f, 0.f);

    for (int k0 = 0; k0 < HN; k0 += 16) {
        xs[lk + 0][lr] = xv.x; xs[lk + 1][lr] = xv.y; xs[lk + 2][lr] = xv.z; xs[lk + 3][lr] = xv.w;
        wsm[lk + 0][lr] = wv.x; wsm[lk + 1][lr] = wv.y; wsm[lk + 2][lr] = wv.z; wsm[lk + 3][lr] = wv.w;
        __syncthreads();
        if (k0 + 16 < HN) {                  // prefetch next tile during MACs
            xv = *(const float4*)(X + (size_t)(m0 + lr) * HN + k0 + 16 + lk);
            if (wok) wv = *(const float4*)(W + (size_t)(n0 + lr) * HN + k0 + 16 + lk);
        }
#pragma unroll
        for (int kk = 0; kk < 16; ++kk) {
            const float4 a4 = *(const float4*)&xs[kk][ty * 4];
            const float4 b4 = *(const float4*)&wsm[kk][tx * 4];
            c[0][0] += a4.x * b4.x; c[0][1] += a4.x * b4.y; c[0][2] += a4.x * b4.z; c[0][3] += a4.x * b4.w;
            c[1][0] += a4.y * b4.x; c[1][1] += a4.y * b4.y; c[1][2] += a4.y * b4.z; c[1][3] += a4.y * b4.w;
            c[2][0] += a4.z * b4.x; c[2][1] += a4.z * b4.y; c[2][2] += a4.z * b4.z; c[2][3] += a4.z * b4.w;
            c[3][0] += a4.w * b4.x; c[3][1] += a4.w * b4.y; c[3][2] += a4.w * b4.z; c[3][3] += a4.w * b4.w;
        }
        __syncthreads();
    }
#pragma unroll
    for (int i = 0; i < 4; ++i) {
        const int m = m0 + ty * 4 + i;
#pragma unroll
        for (int j = 0; j < 4; ++j) {
            const int n = n0 + tx * 4 + j;
            if (n < G3) out[(size_t)m * G3 + n] = c[i][j] + bias[n];
        }
    }
}

// ---------------------------------------------------------------------------
// Phase 1b: decoder input-projection table
// ---------------------------------------------------------------------------
__global__ __launch_bounds__(256) void table_k(const float* __restrict__ emb,
                                               const float* __restrict__ Wih,
                                               const float* __restrict__ bih,
                                               float* __restrict__ tab)
{
    const int idx = blockIdx.x * 256 + threadIdx.x;  // 456*256 = 116736 = 128*912
    const int d = idx / G3;
    const int R = idx - d * G3;
    const float4* e4 = (const float4*)(emb + (size_t)d * HN);
    const float4* w4 = (const float4*)(Wih + (size_t)R * HN);
    float acc = 0.f;
#pragma unroll
    for (int j = 0; j < 76; ++j) {
        const float4 e = e4[j], w = w4[j];
        acc += e.x * w.x; acc += e.y * w.y; acc += e.z * w.z; acc += e.w * w.w;
    }
    tab[idx] = acc + bih[R];
}

// target_cal output
__global__ void tcal_k(const int* __restrict__ target, float* __restrict__ out)
{
    const int i = blockIdx.x * 256 + threadIdx.x;
    if (i < NB * LDEC) {
        const int b = i / LDEC;
        const int t = i - b * LDEC;
        out[OUT_O1 + i] = (float)target[b * 128 + t + 1];
    }
}

// Pipelined self-tagged poll: keep 3 loads in flight so detection granularity
// is ~RTT/3 instead of ~RTT. Relaxed-only (no acquire -> no buffer_inv).
// Any value with matching mod-4 tag is the wanted one (slot reuse distance 2).
__device__ __forceinline__ unsigned poll_tag32p(unsigned int* p, unsigned want, int* abortf)
{
    unsigned v0 = __hip_atomic_load(p, __ATOMIC_RELAXED, __HIP_MEMORY_SCOPE_AGENT);
    unsigned v1 = __hip_atomic_load(p, __ATOMIC_RELAXED, __HIP_MEMORY_SCOPE_AGENT);
    unsigned v2 = __hip_atomic_load(p, __ATOMIC_RELAXED, __HIP_MEMORY_SCOPE_AGENT);
    int g = 0;
    while ((v0 & 3u) != want) {
        v0 = v1; v1 = v2;
        v2 = __hip_atomic_load(p, __ATOMIC_RELAXED, __HIP_MEMORY_SCOPE_AGENT);
        if ((++g & 255) == 0) {
            if (__hip_atomic_load(abortf, __ATOMIC_RELAXED, __HIP_MEMORY_SCOPE_AGENT) != 0) break;
            if (g > (1 << 19)) {  // deadlock valve: fail loudly, don't hang
                __hip_atomic_store(abortf, 1, __ATOMIC_RELAXED, __HIP_MEMORY_SCOPE_AGENT);
                break;
            }
        }
    }
    __asm__ volatile("" ::: "memory");
    return v0;
}

// tagged 8B poll for argmax: wait until tag (high 32b, signed) >= want
__device__ __forceinline__ unsigned long long spin_tag(unsigned long long* p, int want, int* abortf)
{
    int g = 0;
    unsigned long long r;
    for (;;) {
        r = __hip_atomic_load(p, __ATOMIC_RELAXED, __HIP_MEMORY_SCOPE_AGENT);
        if ((int)(r >> 32) >= want) break;
        if ((++g & 255) == 0) {
            if (__hip_atomic_load(abortf, __ATOMIC_RELAXED, __HIP_MEMORY_SCOPE_AGENT) != 0) break;
            if (g > (1 << 19)) {
                __hip_atomic_store(abortf, 1, __ATOMIC_RELAXED, __HIP_MEMORY_SCOPE_AGENT);
                break;
            }
        }
    }
    __asm__ volatile("" ::: "memory");
    return r;
}

// ---------------------------------------------------------------------------
// Phase 2: persistent recurrence. 256 WGs x 1024 threads, 1 WG/CU.
// WG w: batch b = w & 63, slice s = w >> 6.
// h exchange: self-tagged elements (R5 protocol, unchanged). Changes this round:
//  * pipelined 3-deep polls (detection ~RTT/3)
//  * encoder gi prefetched one step ahead (register ping-pong, never exposed)
//  * decoder: amax(t-1) polled by idle threads 960..963 DURING step t's GEMV;
//    act reads tab[tok_s] directly. Removes the serial argmax exchange.
//    asr_outputs written at the poll site (t-1), final t=126 after the loop.
// Thread roles (disjoint): tid<76 act+gi; tid<912 GEMV; tid<304&&cq!=s h-poll;
// tid 960..963 amax poll; tid<256 logits; tid<32 logit reduce; tid0 amax publish.
// ---------------------------------------------------------------------------
__global__ __launch_bounds__(1024) void rnn_persist(
    const float* __restrict__ gi,
    const float* __restrict__ encWhh, const float* __restrict__ encBhh,
    const float* __restrict__ decWhh, const float* __restrict__ decBhh,
    const float* __restrict__ tab,
    const float* __restrict__ linW, const float* __restrict__ linB,
    const int* __restrict__ target,
    unsigned int* hpk, unsigned long long* amax, int* abortf, float* out)
{
    const int w = blockIdx.x;
    const int b = w & 63;
    const int s = w >> 6;
    const int tid = threadIdx.x;

    __shared__ alignas(16) float hbuf[HN];
    __shared__ alignas(16) float part[4][RS];
    __shared__ alignas(16) float lpart[32][9];
    __shared__ float logit_s[32];
    __shared__ float amx_v[4];
    __shared__ int   amx_i[4];
    __shared__ int   tok_s;

    const int ks = tid / RS;           // k-slice 0..3 (tid>=912 idle in GEMV)
    const int lr = tid - ks * RS;      // local row 0..227
    const bool comp = (tid < 912);
    const int g = lr / US;             // gate 0=r,1=z,2=n
    const int ul = lr - g * US;        // unit within slice
    const int Rrow = g * HN + s * US + ul;
    const int u = s * US + tid;        // global hidden unit for tid<76
    const int cq = tid / US;           // slice owning element `tid` (tid<304)

    unsigned long long* amx = amax + b * 4;
    unsigned int* hpb = hpk + b * HN;  // parity stride = NB*HN

    // ---- encoder Whh slice into registers (76 f32 per thread)
    float4 wreg[19];
    if (comp) {
        const float4* wp = (const float4*)(encWhh + (size_t)Rrow * HN + (size_t)ks * US);
#pragma unroll
        for (int j = 0; j < 19; ++j) wreg[j] = wp[j];
    }
    float b_r = 0.f, b_z = 0.f, b_n = 0.f;
    if (tid < US) { b_r = encBhh[u]; b_z = encBhh[HN + u]; b_n = encBhh[2 * HN + u]; }

    for (int i = tid; i < HN; i += 1024) hbuf[i] = 0.f;   // h0 = 0
    __syncthreads();

    const float* gib = gi + (size_t)b * TSTEPS * G3;

    // gi for t=0 (prefetch pipeline seed)
    float gr = 0.f, gz = 0.f, gn = 0.f;
    if (tid < US) { gr = gib[u]; gz = gib[HN + u]; gn = gib[2 * HN + u]; }

    // ================= encoder: 1024 steps =================
    for (int t = 0; t < TSTEPS; ++t) {
        const int T = t + 1;                  // tag of the h this step produces
        float grn = 0.f, gzn = 0.f, gnn = 0.f;
        if (tid < US && t + 1 < TSTEPS) {     // prefetch gi for t+1 (hidden by whole step)
            const float* gp = gib + (size_t)(t + 1) * G3;
            grn = gp[u]; gzn = gp[HN + u]; gnn = gp[2 * HN + u];
        }
        if (comp) {                           // GEMV over h_t in hbuf (LDS broadcast)
            const float4* hp = (const float4*)(hbuf + ks * US);
            float acc = 0.f;
#pragma unroll
            for (int j = 0; j < 19; ++j) {
                const float4 h4 = hp[j], w4 = wreg[j];
                acc += w4.x * h4.x; acc += w4.y * h4.y; acc += w4.z * h4.z; acc += w4.w * h4.w;
            }
            part[ks][lr] = acc;
        }
        __syncthreads();                      // barrier 1: part done, hbuf reads done
        if (tid < US) {
            const float ghr = part[0][tid] + part[1][tid] + part[2][tid] + part[3][tid] + b_r;
            const float ghz = part[0][US + tid] + part[1][US + tid] + part[2][US + tid] + part[3][US + tid] + b_z;
            const float ghn = part[0][2 * US + tid] + part[1][2 * US + tid] + part[2][2 * US + tid] + part[3][2 * US + tid] + b_n;
            const float r = 1.f / (1.f + expf(-(gr + ghr)));
            const float z = 1.f / (1.f + expf(-(gz + ghz)));
            const float n = tanhf(gn + r * ghn);
            const float hnew = (1.f - z) * n + z * hbuf[u];
            const unsigned hb = (__float_as_uint(hnew) & ~3u) | ((unsigned)T & 3u);
            hbuf[u] = __uint_as_float(hb);    // own slice, tagged (bit-identical everywhere)
            __hip_atomic_store(&hpb[(T & 1) * NB * HN + u], hb,
                               __ATOMIC_RELAXED, __HIP_MEMORY_SCOPE_AGENT);
        }
        if (tid < HN && cq != s) {            // fetch remote slices: data IS the flag
            const unsigned v = poll_tag32p(&hpb[(T & 1) * NB * HN + tid],
                                           (unsigned)T & 3u, abortf);
            hbuf[tid] = __uint_as_float(v);
        }
        __syncthreads();                      // barrier 2: hbuf = h_{t+1}
        gr = grn; gz = gzn; gn = gnn;         // rotate gi pipeline
    }

    // ---- decoder weights + biases
    if (comp) {
        const float4* wp = (const float4*)(decWhh + (size_t)Rrow * HN + (size_t)ks * US);
#pragma unroll
        for (int j = 0; j < 19; ++j) wreg[j] = wp[j];
    }
    if (tid < US) { b_r = decBhh[u]; b_z = decBhh[HN + u]; b_n = decBhh[2 * HN + u]; }
    const int tok0 = target[b * 128];  // target[b,0,0]
    const int lrow = tid >> 3;         // logit row within slice (tid<256)
    const int lks = tid & 7;           // 8 k-slices of 38
    __syncthreads();

    // ================= decoder: 127 steps =================
    for (int t = 0; t < LDEC; ++t) {
        const int T = TSTEPS + 1 + t;         // h tag this step produces

        // amax(t-1) poll on idle lanes 960..963 (one wave), concurrent with GEMV
        if (t > 0 && tid >= 960 && tid < 964) {
            const int q = tid - 960;
            const unsigned long long r = spin_tag(&amx[q], t << 8, abortf);
            amx_v[q] = __uint_as_float((unsigned)r);
            amx_i[q] = (int)(r >> 32) & 255;
            // lanes of one wave execute in lockstep; ds writes retire before next instr reads
            if (q == 0) {
                float gbv = amx_v[0]; int gbi = amx_i[0];
                if (amx_v[1] > gbv) { gbv = amx_v[1]; gbi = amx_i[1]; }
                if (amx_v[2] > gbv) { gbv = amx_v[2]; gbi = amx_i[2]; }
                if (amx_v[3] > gbv) { gbv = amx_v[3]; gbi = amx_i[3]; }
                tok_s = gbi;
                if (s == 0) out[OUT_O2 + (size_t)b * LDEC + (t - 1)] = (float)gbi;  // asr_outputs
            }
        }
        if (comp) {                           // GEMV over fresh h in hbuf
            const float4* hp = (const float4*)(hbuf + ks * US);
            float acc = 0.f;
#pragma unroll
            for (int j = 0; j < 19; ++j) {
                const float4 h4 = hp[j], w4 = wreg[j];
                acc += w4.x * h4.x; acc += w4.y * h4.y; acc += w4.z * h4.z; acc += w4.w * h4.w;
            }
            part[ks][lr] = acc;
        }
        __syncthreads();                      // part done; tok_s visible
        if (tid < US) {
            const int tk = (t == 0) ? tok0 : tok_s;
            const float* tp = tab + (size_t)tk * G3;
            const float dgr = tp[u], dgz = tp[HN + u], dgn = tp[2 * HN + u];
            const float ghr = part[0][tid] + part[1][tid] + part[2][tid] + part[3][tid] + b_r;
            const float ghz = part[0][US + tid] + part[1][US + tid] + part[2][US + tid] + part[3][US + tid] + b_z;
            const float ghn = part[0][2 * US + tid] + part[1][2 * US + tid] + part[2][2 * US + tid] + part[3][2 * US + tid] + b_n;
            const float r = 1.f / (1.f + expf(-(dgr + ghr)));
            const float z = 1.f / (1.f + expf(-(dgz + ghz)));
            const float n = tanhf(dgn + r * ghn);
            const float hnew = (1.f - z) * n + z * hbuf[u];
            const unsigned hb = (__float_as_uint(hnew) & ~3u) | ((unsigned)T & 3u);
            hbuf[u] = __uint_as_float(hb);
            __hip_atomic_store(&hpb[(T & 1) * NB * HN + u], hb,
                               __ATOMIC_RELAXED, __HIP_MEMORY_SCOPE_AGENT);
        }
        if (tid < HN && cq != s) {
            const unsigned v = poll_tag32p(&hpb[(T & 1) * NB * HN + tid],
                                           (unsigned)T & 3u, abortf);
            hbuf[tid] = __uint_as_float(v);
        }
        __syncthreads();                      // hbuf = fresh h for logits + next GEMV

        // logits rows [32s, 32s+32)
        if (tid < 256) {
            const float2* wl = (const float2*)(linW + (size_t)(s * 32 + lrow) * HN + (size_t)lks * 38);
            const float2* hl = (const float2*)(hbuf + lks * 38);
            float a = 0.f;
#pragma unroll
            for (int j = 0; j < 19; ++j) { const float2 wv = wl[j], hv = hl[j]; a += wv.x * hv.x; a += wv.y * hv.y; }
            lpart[lrow][lks] = a;
        }
        __syncthreads();
        if (tid < 32) {
            const float lg = lpart[tid][0] + lpart[tid][1] + lpart[tid][2] + lpart[tid][3]
                           + lpart[tid][4] + lpart[tid][5] + lpart[tid][6] + lpart[tid][7]
                           + linB[s * 32 + tid];
            logit_s[tid] = lg;
            out[((size_t)b * LDEC + t) * DCLS + s * 32 + tid] = lg;   // softmax_cal
        }
        __syncthreads();                      // logit_s complete for tid0
        if (tid == 0) {                       // publish local argmax: one tagged 8B store
            float bv = logit_s[0]; int bi = 0;
            for (int i = 1; i < 32; ++i) { const float v = logit_s[i]; if (v > bv) { bv = v; bi = i; } }
            const unsigned tagf = (unsigned)(((t + 1) << 8) | (s * 32 + bi));
            const unsigned long long pk = ((unsigned long long)tagf << 32) | (unsigned long long)__float_as_uint(bv);
            __hip_atomic_store(&amx[s], pk, __ATOMIC_RELAXED, __HIP_MEMORY_SCOPE_AGENT);
        }
        // no trailing barrier: next GEMV reads hbuf (stable); part/lpart/logit_s
        // are each re-written only after a barrier in the next iteration.
    }

    // final winner (t = LDEC-1) for asr_outputs
    if (s == 0 && tid == 0) {
        float gbv = 0.f; int gbi = 0;
        for (int q = 0; q < 4; ++q) {   // ascending q + strict '>' == first-max tie-break
            const unsigned long long r = spin_tag(&amx[q], LDEC << 8, abortf);
            const float v = __uint_as_float((unsigned)r);
            const int ii = (int)(r >> 32) & 255;
            if (q == 0 || v > gbv) { gbv = v; gbi = ii; }
        }
        out[OUT_O2 + (size_t)b * LDEC + (LDEC - 1)] = (float)gbi;
    }
}

// ---------------------------------------------------------------------------
extern "C" void kernel_launch(void* const* d_in, const int* in_sizes, int n_in,
                              void* d_out, int out_size, void* d_ws, size_t ws_size,
                              hipStream_t stream)
{
    (void)in_sizes; (void)n_in; (void)out_size;
    const float* x      = (const float*)d_in[0];
    const int*   target = (const int*)  d_in[1];
    const float* emb    = (const float*)d_in[2];
    const float* encWih = (const float*)d_in[3];
    const float* encWhh = (const float*)d_in[4];
    const float* encBih = (const float*)d_in[5];
    const float* encBhh = (const float*)d_in[6];
    const float* decWih = (const float*)d_in[7];
    const float* decWhh = (const float*)d_in[8];
    const float* decBih = (const float*)d_in[9];
    const float* decBhh = (const float*)d_in[10];
    const float* linW   = (const float*)d_in[11];
    const float* linB   = (const float*)d_in[12];
    float* out = (float*)d_out;
    char* ws = (char*)d_ws;

    if (ws_size < WS_NEED) return;  // insufficient scratch: fail visibly

    float*              gi   = (float*)(ws + OFF_GI);
    unsigned int*       hpk  = (unsigned int*)(ws + OFF_HP);
    unsigned long long* amax = (unsigned long long*)(ws + OFF_AM);
    int*                abrt = (int*)(ws + OFF_ABRT);
    float*              tab  = (float*)(ws + OFF_TAB);

    // zero tagged-h ping-pong (tag 0 = "unwritten"), argmax slots, abort flag
    hipMemsetAsync(ws + OFF_HP, 0, OFF_TAB - OFF_HP, stream);
    gi_gemm<<<dim3(1024, 15), 256, 0, stream>>>(x, encWih, encBih, gi);
    table_k<<<456, 256, 0, stream>>>(emb, decWih, decBih, tab);
    tcal_k<<<32, 256, 0, stream>>>(target, out);
    rnn_persist<<<256, 1024, 0, stream>>>(gi, encWhh, encBhh, decWhh, decBhh, tab,
                                          linW, linB, target, hpk, amax, abrt, out);
}

// Round 7
// 3142.624 us; speedup vs baseline: 1.1178x; 1.1178x over previous
//
#include <hip/hip_runtime.h>
#include <cstdint>
#include <cstddef>

// Problem constants
#define HN 304      // hidden size
#define G3 912      // 3*HN gate rows
#define US 76       // hidden units per slice (HN/4)
#define RS 228      // rows per slice (3*US)
#define NB 64       // batch
#define TSTEPS 1024 // encoder steps
#define LDEC 127    // decoder steps actually needed (L-1)
#define DCLS 128    // vocab / classes

// Output layout (floats): [softmax_cal 8128*128][target_cal 8128][asr_outputs 8128]
#define OUT_O1 1040384
#define OUT_O2 1048512

// Workspace layout (bytes). Proven available: ws_size >= 239,702,784 (R1-R6 ran).
static const size_t OFF_GI   = 0;             // 64*1024*912 f32 = 239,075,328
static const size_t OFF_HP   = 239075328ull;  // tagged h ping-pong: 2*64*304 u32 = 155,648
static const size_t OFF_AM   = 239230976ull;  // argmax tagged: 64*4 ull = 2,048
static const size_t OFF_ABRT = 239233024ull;  // 256
static const size_t OFF_TAB  = 239233280ull;  // 128*912 f32 = 466,944
static const size_t WS_NEED  = 239700224ull;  // <= proven bound

// ---------------------------------------------------------------------------
// Phase 1: gi[b,t,:] = x[b,t,:] @ enc_Wih^T + enc_bih   (M=65536, N=912, K=304)
// Reg-double-buffered global loads (neutral-measured R6 version).
// ---------------------------------------------------------------------------
__global__ __launch_bounds__(256) void gi_gemm(const float* __restrict__ X,
                                               const float* __restrict__ W,
                                               const float* __restrict__ bias,
                                               float* __restrict__ out)
{
    __shared__ float xs[16][68];
    __shared__ float wsm[16][68];
    const int tid = threadIdx.x;
    const int m0 = blockIdx.x * 64;
    const int n0 = blockIdx.y * 64;
    const int tx = tid & 15, ty = tid >> 4;
    const int lr = tid >> 2;
    const int lk = (tid & 3) * 4;
    float c[4][4];
#pragma unroll
    for (int i = 0; i < 4; ++i)
#pragma unroll
        for (int j = 0; j < 4; ++j) c[i][j] = 0.f;

    const bool wok = (n0 + lr < G3);
    float4 xv = *(const float4*)(X + (size_t)(m0 + lr) * HN + lk);
    float4 wv = wok ? *(const float4*)(W + (size_t)(n0 + lr) * HN + lk)
                    : make_float4(0.f, 0.f, 0.f, 0.f);

    for (int k0 = 0; k0 < HN; k0 += 16) {
        xs[lk + 0][lr] = xv.x; xs[lk + 1][lr] = xv.y; xs[lk + 2][lr] = xv.z; xs[lk + 3][lr] = xv.w;
        wsm[lk + 0][lr] = wv.x; wsm[lk + 1][lr] = wv.y; wsm[lk + 2][lr] = wv.z; wsm[lk + 3][lr] = wv.w;
        __syncthreads();
        if (k0 + 16 < HN) {                  // prefetch next tile during MACs
            xv = *(const float4*)(X + (size_t)(m0 + lr) * HN + k0 + 16 + lk);
            if (wok) wv = *(const float4*)(W + (size_t)(n0 + lr) * HN + k0 + 16 + lk);
        }
#pragma unroll
        for (int kk = 0; kk < 16; ++kk) {
            const float4 a4 = *(const float4*)&xs[kk][ty * 4];
            const float4 b4 = *(const float4*)&wsm[kk][tx * 4];
            c[0][0] += a4.x * b4.x; c[0][1] += a4.x * b4.y; c[0][2] += a4.x * b4.z; c[0][3] += a4.x * b4.w;
            c[1][0] += a4.y * b4.x; c[1][1] += a4.y * b4.y; c[1][2] += a4.y * b4.z; c[1][3] += a4.y * b4.w;
            c[2][0] += a4.z * b4.x; c[2][1] += a4.z * b4.y; c[2][2] += a4.z * b4.z; c[2][3] += a4.z * b4.w;
            c[3][0] += a4.w * b4.x; c[3][1] += a4.w * b4.y; c[3][2] += a4.w * b4.z; c[3][3] += a4.w * b4.w;
        }
        __syncthreads();
    }
#pragma unroll
    for (int i = 0; i < 4; ++i) {
        const int m = m0 + ty * 4 + i;
#pragma unroll
        for (int j = 0; j < 4; ++j) {
            const int n = n0 + tx * 4 + j;
            if (n < G3) out[(size_t)m * G3 + n] = c[i][j] + bias[n];
        }
    }
}

// ---------------------------------------------------------------------------
// Phase 1b: decoder input-projection table
// ---------------------------------------------------------------------------
__global__ __launch_bounds__(256) void table_k(const float* __restrict__ emb,
                                               const float* __restrict__ Wih,
                                               const float* __restrict__ bih,
                                               float* __restrict__ tab)
{
    const int idx = blockIdx.x * 256 + threadIdx.x;  // 456*256 = 116736 = 128*912
    const int d = idx / G3;
    const int R = idx - d * G3;
    const float4* e4 = (const float4*)(emb + (size_t)d * HN);
    const float4* w4 = (const float4*)(Wih + (size_t)R * HN);
    float acc = 0.f;
#pragma unroll
    for (int j = 0; j < 76; ++j) {
        const float4 e = e4[j], w = w4[j];
        acc += e.x * w.x; acc += e.y * w.y; acc += e.z * w.z; acc += e.w * w.w;
    }
    tab[idx] = acc + bih[R];
}

// target_cal output
__global__ void tcal_k(const int* __restrict__ target, float* __restrict__ out)
{
    const int i = blockIdx.x * 256 + threadIdx.x;
    if (i < NB * LDEC) {
        const int b = i / LDEC;
        const int t = i - b * LDEC;
        out[OUT_O1 + i] = (float)target[b * 128 + t + 1];
    }
}

// Self-tagged poll (R5 form: single outstanding load — 3-deep variant regressed).
__device__ __forceinline__ unsigned poll_tag32(unsigned int* p, unsigned want, int* abortf)
{
    unsigned v; int g = 0;
    for (;;) {
        v = __hip_atomic_load(p, __ATOMIC_RELAXED, __HIP_MEMORY_SCOPE_AGENT);
        if ((v & 3u) == want) break;
        if ((++g & 255) == 0) {
            if (__hip_atomic_load(abortf, __ATOMIC_RELAXED, __HIP_MEMORY_SCOPE_AGENT) != 0) break;
            if (g > (1 << 19)) {  // deadlock valve: fail loudly, don't hang
                __hip_atomic_store(abortf, 1, __ATOMIC_RELAXED, __HIP_MEMORY_SCOPE_AGENT);
                break;
            }
        }
    }
    __asm__ volatile("" ::: "memory");
    return v;
}

// tagged 8B poll for argmax: wait until tag (high 32b, signed) >= want
__device__ __forceinline__ unsigned long long spin_tag(unsigned long long* p, int want, int* abortf)
{
    int g = 0;
    unsigned long long r;
    for (;;) {
        r = __hip_atomic_load(p, __ATOMIC_RELAXED, __HIP_MEMORY_SCOPE_AGENT);
        if ((int)(r >> 32) >= want) break;
        if ((++g & 255) == 0) {
            if (__hip_atomic_load(abortf, __ATOMIC_RELAXED, __HIP_MEMORY_SCOPE_AGENT) != 0) break;
            if (g > (1 << 19)) {
                __hip_atomic_store(abortf, 1, __ATOMIC_RELAXED, __HIP_MEMORY_SCOPE_AGENT);
                break;
            }
        }
    }
    __asm__ volatile("" ::: "memory");
    return r;
}

// ---------------------------------------------------------------------------
// Phase 2: persistent recurrence. 256 WGs x 512 threads, 1 WG/CU.
// WG w: batch b = w & 63, slice s = w >> 6.
// R7 change vs R5: GEMV restructured to 2 rows/thread x 76 k (456 threads,
// 152 weight f32/thread): each ds_read_b128 of h feeds 8 FMAs instead of 4,
// halving LDS-read instructions (271 -> 135 per WG-step) — the step's largest
// issue-cost term. part[4][228] layout and per-row k-ascending accumulation
// unchanged -> bit-identical results. Block 512 (__launch_bounds__(512,2)):
// 2 waves/SIMD, VGPR cap 256 for the ~190-reg weight-resident threads.
// h exchange: R5 self-tagged protocol, verbatim.
// ---------------------------------------------------------------------------
__global__ __launch_bounds__(512, 2) void rnn_persist(
    const float* __restrict__ gi,
    const float* __restrict__ encWhh, const float* __restrict__ encBhh,
    const float* __restrict__ decWhh, const float* __restrict__ decBhh,
    const float* __restrict__ tab,
    const float* __restrict__ linW, const float* __restrict__ linB,
    const int* __restrict__ target,
    unsigned int* hpk, unsigned long long* amax, int* abortf, float* out)
{
    const int w = blockIdx.x;
    const int b = w & 63;
    const int s = w >> 6;
    const int tid = threadIdx.x;

    __shared__ alignas(16) float hbuf[HN];
    __shared__ alignas(16) float part[4][RS];
    __shared__ alignas(16) float lpart[32][9];
    __shared__ float logit_s[32];
    __shared__ float amx_v[4];
    __shared__ int   amx_i[4];

    const bool comp = (tid < 456);
    const int ksq = tid / 114;          // k-group 0..3 (k-window [76*ksq, 76*ksq+76))
    const int lp  = tid - ksq * 114;    // row-pair index 0..113; rows lp and lp+114
    // row -> gate/unit mapping (row lr in [0,228): gate g = lr/76, unit ul = lr%76)
    const int g0 = lp / US,        ul0 = lp - g0 * US;
    const int g1 = (lp + 114) / US, ul1 = (lp + 114) - g1 * US;
    const int Rrow0 = g0 * HN + s * US + ul0;
    const int Rrow1 = g1 * HN + s * US + ul1;
    const int u = s * US + tid;         // global hidden unit for tid<76
    const int cq = tid / US;            // slice owning element `tid` (tid<304)

    unsigned long long* amx = amax + b * 4;
    unsigned int* hpb = hpk + b * HN;   // parity stride = NB*HN

    // ---- encoder Whh: 2 rows x 76 k per thread (152 f32 in registers)
    float4 wreg0[19], wreg1[19];
    if (comp) {
        const float4* wp0 = (const float4*)(encWhh + (size_t)Rrow0 * HN + (size_t)ksq * US);
        const float4* wp1 = (const float4*)(encWhh + (size_t)Rrow1 * HN + (size_t)ksq * US);
#pragma unroll
        for (int j = 0; j < 19; ++j) { wreg0[j] = wp0[j]; wreg1[j] = wp1[j]; }
    }
    float b_r = 0.f, b_z = 0.f, b_n = 0.f;
    if (tid < US) { b_r = encBhh[u]; b_z = encBhh[HN + u]; b_n = encBhh[2 * HN + u]; }

    for (int i = tid; i < HN; i += 512) hbuf[i] = 0.f;   // h0 = 0
    __syncthreads();

    const float* gib = gi + (size_t)b * TSTEPS * G3;

    // ================= encoder: 1024 steps =================
    for (int t = 0; t < TSTEPS; ++t) {
        const int T = t + 1;                  // tag of the h this step produces
        float gr = 0.f, gz = 0.f, gn = 0.f;
        if (tid < US) {                       // gi load, hidden behind GEMV
            const float* gp = gib + (size_t)t * G3;
            gr = gp[u]; gz = gp[HN + u]; gn = gp[2 * HN + u];
        }
        if (comp) {                           // GEMV: 2 rows per thread, shared h reads
            const float4* hp = (const float4*)(hbuf + ksq * US);
            float acc0 = 0.f, acc1 = 0.f;
#pragma unroll
            for (int j = 0; j < 19; ++j) {
                const float4 h4 = hp[j];
                const float4 w0 = wreg0[j], w1 = wreg1[j];
                acc0 += w0.x * h4.x; acc0 += w0.y * h4.y; acc0 += w0.z * h4.z; acc0 += w0.w * h4.w;
                acc1 += w1.x * h4.x; acc1 += w1.y * h4.y; acc1 += w1.z * h4.z; acc1 += w1.w * h4.w;
            }
            part[ksq][lp] = acc0;
            part[ksq][lp + 114] = acc1;
        }
        __syncthreads();                      // barrier 1: part done, hbuf reads done
        if (tid < US) {
            const float ghr = part[0][tid] + part[1][tid] + part[2][tid] + part[3][tid] + b_r;
            const float ghz = part[0][US + tid] + part[1][US + tid] + part[2][US + tid] + part[3][US + tid] + b_z;
            const float ghn = part[0][2 * US + tid] + part[1][2 * US + tid] + part[2][2 * US + tid] + part[3][2 * US + tid] + b_n;
            const float r = 1.f / (1.f + expf(-(gr + ghr)));
            const float z = 1.f / (1.f + expf(-(gz + ghz)));
            const float n = tanhf(gn + r * ghn);
            const float hnew = (1.f - z) * n + z * hbuf[u];
            const unsigned hb = (__float_as_uint(hnew) & ~3u) | ((unsigned)T & 3u);
            hbuf[u] = __uint_as_float(hb);    // own slice, tagged (bit-identical everywhere)
            __hip_atomic_store(&hpb[(T & 1) * NB * HN + u], hb,
                               __ATOMIC_RELAXED, __HIP_MEMORY_SCOPE_AGENT);
        }
        if (tid < HN && cq != s) {            // fetch remote slices: data IS the flag
            const unsigned v = poll_tag32(&hpb[(T & 1) * NB * HN + tid],
                                          (unsigned)T & 3u, abortf);
            hbuf[tid] = __uint_as_float(v);
        }
        __syncthreads();                      // barrier 2: hbuf = h_{t+1}
    }

    // ---- decoder weights + biases
    if (comp) {
        const float4* wp0 = (const float4*)(decWhh + (size_t)Rrow0 * HN + (size_t)ksq * US);
        const float4* wp1 = (const float4*)(decWhh + (size_t)Rrow1 * HN + (size_t)ksq * US);
#pragma unroll
        for (int j = 0; j < 19; ++j) { wreg0[j] = wp0[j]; wreg1[j] = wp1[j]; }
    }
    if (tid < US) { b_r = decBhh[u]; b_z = decBhh[HN + u]; b_n = decBhh[2 * HN + u]; }
    int tok = target[b * 128];         // target[b,0,0]
    const int lrow = tid >> 3;         // logit row within slice (tid<256)
    const int lks = tid & 7;           // 8 k-slices of 38
    __syncthreads();

    // ================= decoder: 127 steps =================
    for (int t = 0; t < LDEC; ++t) {
        const int T = TSTEPS + 1 + t;         // h tag this step produces
        float gr = 0.f, gz = 0.f, gn = 0.f;
        if (tid < US) {
            const float* tp = tab + (size_t)tok * G3;
            gr = tp[u]; gz = tp[HN + u]; gn = tp[2 * HN + u];
        }
        if (comp) {
            const float4* hp = (const float4*)(hbuf + ksq * US);
            float acc0 = 0.f, acc1 = 0.f;
#pragma unroll
            for (int j = 0; j < 19; ++j) {
                const float4 h4 = hp[j];
                const float4 w0 = wreg0[j], w1 = wreg1[j];
                acc0 += w0.x * h4.x; acc0 += w0.y * h4.y; acc0 += w0.z * h4.z; acc0 += w0.w * h4.w;
                acc1 += w1.x * h4.x; acc1 += w1.y * h4.y; acc1 += w1.z * h4.z; acc1 += w1.w * h4.w;
            }
            part[ksq][lp] = acc0;
            part[ksq][lp + 114] = acc1;
        }
        __syncthreads();
        if (tid < US) {
            const float ghr = part[0][tid] + part[1][tid] + part[2][tid] + part[3][tid] + b_r;
            const float ghz = part[0][US + tid] + part[1][US + tid] + part[2][US + tid] + part[3][US + tid] + b_z;
            const float ghn = part[0][2 * US + tid] + part[1][2 * US + tid] + part[2][2 * US + tid] + part[3][2 * US + tid] + b_n;
            const float r = 1.f / (1.f + expf(-(gr + ghr)));
            const float z = 1.f / (1.f + expf(-(gz + ghz)));
            const float n = tanhf(gn + r * ghn);
            const float hnew = (1.f - z) * n + z * hbuf[u];
            const unsigned hb = (__float_as_uint(hnew) & ~3u) | ((unsigned)T & 3u);
            hbuf[u] = __uint_as_float(hb);
            __hip_atomic_store(&hpb[(T & 1) * NB * HN + u], hb,
                               __ATOMIC_RELAXED, __HIP_MEMORY_SCOPE_AGENT);
        }
        if (tid < HN && cq != s) {
            const unsigned v = poll_tag32(&hpb[(T & 1) * NB * HN + tid],
                                          (unsigned)T & 3u, abortf);
            hbuf[tid] = __uint_as_float(v);
        }
        __syncthreads();                      // hbuf = fresh h for logits

        // logits rows [32s, 32s+32)
        if (tid < 256) {
            const float2* wl = (const float2*)(linW + (size_t)(s * 32 + lrow) * HN + (size_t)lks * 38);
            const float2* hl = (const float2*)(hbuf + lks * 38);
            float a = 0.f;
#pragma unroll
            for (int j = 0; j < 19; ++j) { const float2 wv = wl[j], hv = hl[j]; a += wv.x * hv.x; a += wv.y * hv.y; }
            lpart[lrow][lks] = a;
        }
        __syncthreads();
        if (tid < 32) {
            const float lg = lpart[tid][0] + lpart[tid][1] + lpart[tid][2] + lpart[tid][3]
                           + lpart[tid][4] + lpart[tid][5] + lpart[tid][6] + lpart[tid][7]
                           + linB[s * 32 + tid];
            logit_s[tid] = lg;
            out[((size_t)b * LDEC + t) * DCLS + s * 32 + tid] = lg;   // softmax_cal
        }
        __syncthreads();
        if (tid == 0) {                       // publish local argmax: one tagged 8B store
            float bv = logit_s[0]; int bi = 0;
            for (int i = 1; i < 32; ++i) { const float v = logit_s[i]; if (v > bv) { bv = v; bi = i; } }
            const unsigned tagf = (unsigned)(((t + 1) << 8) | (s * 32 + bi));
            const unsigned long long pk = ((unsigned long long)tagf << 32) | (unsigned long long)__float_as_uint(bv);
            __hip_atomic_store(&amx[s], pk, __ATOMIC_RELAXED, __HIP_MEMORY_SCOPE_AGENT);
        }
        if (tid < 4) {                        // poll all 4 slices' argmaxes in parallel
            const unsigned long long r = spin_tag(&amx[tid], (t + 1) << 8, abortf);
            amx_v[tid] = __uint_as_float((unsigned)r);
            amx_i[tid] = (int)(r >> 32) & 255;
        }
        __syncthreads();
        {                                     // identical winner on all threads
            float gbv = amx_v[0]; int gbi = amx_i[0];
            if (amx_v[1] > gbv) { gbv = amx_v[1]; gbi = amx_i[1]; }
            if (amx_v[2] > gbv) { gbv = amx_v[2]; gbi = amx_i[2]; }
            if (amx_v[3] > gbv) { gbv = amx_v[3]; gbi = amx_i[3]; }
            tok = gbi;
            if (tid == 0 && s == 0) out[OUT_O2 + (size_t)b * LDEC + t] = (float)gbi;  // asr_outputs
        }
    }
}

// ---------------------------------------------------------------------------
extern "C" void kernel_launch(void* const* d_in, const int* in_sizes, int n_in,
                              void* d_out, int out_size, void* d_ws, size_t ws_size,
                              hipStream_t stream)
{
    (void)in_sizes; (void)n_in; (void)out_size;
    const float* x      = (const float*)d_in[0];
    const int*   target = (const int*)  d_in[1];
    const float* emb    = (const float*)d_in[2];
    const float* encWih = (const float*)d_in[3];
    const float* encWhh = (const float*)d_in[4];
    const float* encBih = (const float*)d_in[5];
    const float* encBhh = (const float*)d_in[6];
    const float* decWih = (const float*)d_in[7];
    const float* decWhh = (const float*)d_in[8];
    const float* decBih = (const float*)d_in[9];
    const float* decBhh = (const float*)d_in[10];
    const float* linW   = (const float*)d_in[11];
    const float* linB   = (const float*)d_in[12];
    float* out = (float*)d_out;
    char* ws = (char*)d_ws;

    if (ws_size < WS_NEED) return;  // insufficient scratch: fail visibly

    float*              gi   = (float*)(ws + OFF_GI);
    unsigned int*       hpk  = (unsigned int*)(ws + OFF_HP);
    unsigned long long* amax = (unsigned long long*)(ws + OFF_AM);
    int*                abrt = (int*)(ws + OFF_ABRT);
    float*              tab  = (float*)(ws + OFF_TAB);

    // zero tagged-h ping-pong (tag 0 = "unwritten"), argmax slots, abort flag
    hipMemsetAsync(ws + OFF_HP, 0, OFF_TAB - OFF_HP, stream);
    gi_gemm<<<dim3(1024, 15), 256, 0, stream>>>(x, encWih, encBih, gi);
    table_k<<<456, 256, 0, stream>>>(emb, decWih, decBih, tab);
    tcal_k<<<32, 256, 0, stream>>>(target, out);
    rnn_persist<<<256, 512, 0, stream>>>(gi, encWhh, encBhh, decWhh, decBhh, tab,
                                         linW, linB, target, hpk, amax, abrt, out);
}

// Round 8
// 3085.942 us; speedup vs baseline: 1.1383x; 1.0184x over previous
//
#include <hip/hip_runtime.h>
#include <cstdint>
#include <cstddef>

// Problem constants
#define HN 304      // hidden size
#define G3 912      // 3*HN gate rows
#define US 76       // hidden units per slice (HN/4)
#define RS 228      // rows per slice (3*US)
#define NB 64       // batch
#define TSTEPS 1024 // encoder steps
#define LDEC 127    // decoder steps actually needed (L-1)
#define DCLS 128    // vocab / classes

// Output layout (floats): [softmax_cal 8128*128][target_cal 8128][asr_outputs 8128]
#define OUT_O1 1040384
#define OUT_O2 1048512

// Workspace layout (bytes). Proven available: ws_size >= 239,702,784 (R1-R7 ran).
static const size_t OFF_GI   = 0;             // 64*1024*912 f32 = 239,075,328
static const size_t OFF_HP   = 239075328ull;  // tagged h ping-pong: 2*64*304 u32 = 155,648
static const size_t OFF_AM   = 239230976ull;  // argmax tagged: 64*4 ull = 2,048
static const size_t OFF_ABRT = 239233024ull;  // 256
static const size_t OFF_TAB  = 239233280ull;  // 128*912 f32 = 466,944
static const size_t WS_NEED  = 239700224ull;  // <= proven bound

// ---------------------------------------------------------------------------
// Phase 1: gi[b,t,:] = x[b,t,:] @ enc_Wih^T + enc_bih   (M=65536, N=912, K=304)
// R8: 128x128 block tile, 8x8 accumulator/thread (256 thr). 64 FMA per
// 4 ds_read_b128 (16:1) vs old 8:1 -> VALU-bound ~85% theoretical.
// A/B staged k-major (transposed scalar stores, 2-way = free). Per-element
// accumulation strictly k-ascending -> bit-identical to the 64x64 version.
// Grid (512, 8): N padded 912->1024 (masked B rows = 0, masked stores).
// ---------------------------------------------------------------------------
__global__ __launch_bounds__(256) void gi_gemm(const float* __restrict__ X,
                                               const float* __restrict__ W,
                                               const float* __restrict__ bias,
                                               float* __restrict__ out)
{
    __shared__ float As[16][132];
    __shared__ float Bs[16][132];
    const int tid = threadIdx.x;
    const int m0 = blockIdx.x * 128;
    const int n0 = blockIdx.y * 128;
    const int tx = tid & 15;          // n-dir (8 cols each)
    const int ty = tid >> 4;          // m-dir (8 rows each)
    const int lr = tid >> 1;          // staging row 0..127
    const int lc = (tid & 1) * 8;     // staging k-offset 0 or 8

    float c[8][8];
#pragma unroll
    for (int i = 0; i < 8; ++i)
#pragma unroll
        for (int j = 0; j < 8; ++j) c[i][j] = 0.f;

    const bool wok = (n0 + lr < G3);
    const float* xrow = X + (size_t)(m0 + lr) * HN;
    const float* wrow = W + (size_t)(n0 + lr) * HN;
    const float4 z4 = make_float4(0.f, 0.f, 0.f, 0.f);

    float4 xa = *(const float4*)(xrow + lc);
    float4 xb = *(const float4*)(xrow + lc + 4);
    float4 wa = wok ? *(const float4*)(wrow + lc) : z4;
    float4 wb = wok ? *(const float4*)(wrow + lc + 4) : z4;

    for (int k0 = 0; k0 < HN; k0 += 16) {
        // stage regs -> LDS, k-major (transpose)
        As[lc + 0][lr] = xa.x; As[lc + 1][lr] = xa.y; As[lc + 2][lr] = xa.z; As[lc + 3][lr] = xa.w;
        As[lc + 4][lr] = xb.x; As[lc + 5][lr] = xb.y; As[lc + 6][lr] = xb.z; As[lc + 7][lr] = xb.w;
        Bs[lc + 0][lr] = wa.x; Bs[lc + 1][lr] = wa.y; Bs[lc + 2][lr] = wa.z; Bs[lc + 3][lr] = wa.w;
        Bs[lc + 4][lr] = wb.x; Bs[lc + 5][lr] = wb.y; Bs[lc + 6][lr] = wb.z; Bs[lc + 7][lr] = wb.w;
        __syncthreads();
        if (k0 + 16 < HN) {               // prefetch next K-tile during MACs
            xa = *(const float4*)(xrow + k0 + 16 + lc);
            xb = *(const float4*)(xrow + k0 + 16 + lc + 4);
            if (wok) {
                wa = *(const float4*)(wrow + k0 + 16 + lc);
                wb = *(const float4*)(wrow + k0 + 16 + lc + 4);
            }
        }
#pragma unroll
        for (int kk = 0; kk < 16; ++kk) {
            const float4 a0 = *(const float4*)&As[kk][ty * 8];
            const float4 a1 = *(const float4*)&As[kk][ty * 8 + 4];
            const float4 b0 = *(const float4*)&Bs[kk][tx * 8];
            const float4 b1 = *(const float4*)&Bs[kk][tx * 8 + 4];
            c[0][0] += a0.x * b0.x; c[0][1] += a0.x * b0.y; c[0][2] += a0.x * b0.z; c[0][3] += a0.x * b0.w;
            c[0][4] += a0.x * b1.x; c[0][5] += a0.x * b1.y; c[0][6] += a0.x * b1.z; c[0][7] += a0.x * b1.w;
            c[1][0] += a0.y * b0.x; c[1][1] += a0.y * b0.y; c[1][2] += a0.y * b0.z; c[1][3] += a0.y * b0.w;
            c[1][4] += a0.y * b1.x; c[1][5] += a0.y * b1.y; c[1][6] += a0.y * b1.z; c[1][7] += a0.y * b1.w;
            c[2][0] += a0.z * b0.x; c[2][1] += a0.z * b0.y; c[2][2] += a0.z * b0.z; c[2][3] += a0.z * b0.w;
            c[2][4] += a0.z * b1.x; c[2][5] += a0.z * b1.y; c[2][6] += a0.z * b1.z; c[2][7] += a0.z * b1.w;
            c[3][0] += a0.w * b0.x; c[3][1] += a0.w * b0.y; c[3][2] += a0.w * b0.z; c[3][3] += a0.w * b0.w;
            c[3][4] += a0.w * b1.x; c[3][5] += a0.w * b1.y; c[3][6] += a0.w * b1.z; c[3][7] += a0.w * b1.w;
            c[4][0] += a1.x * b0.x; c[4][1] += a1.x * b0.y; c[4][2] += a1.x * b0.z; c[4][3] += a1.x * b0.w;
            c[4][4] += a1.x * b1.x; c[4][5] += a1.x * b1.y; c[4][6] += a1.x * b1.z; c[4][7] += a1.x * b1.w;
            c[5][0] += a1.y * b0.x; c[5][1] += a1.y * b0.y; c[5][2] += a1.y * b0.z; c[5][3] += a1.y * b0.w;
            c[5][4] += a1.y * b1.x; c[5][5] += a1.y * b1.y; c[5][6] += a1.y * b1.z; c[5][7] += a1.y * b1.w;
            c[6][0] += a1.z * b0.x; c[6][1] += a1.z * b0.y; c[6][2] += a1.z * b0.z; c[6][3] += a1.z * b0.w;
            c[6][4] += a1.z * b1.x; c[6][5] += a1.z * b1.y; c[6][6] += a1.z * b1.z; c[6][7] += a1.z * b1.w;
            c[7][0] += a1.w * b0.x; c[7][1] += a1.w * b0.y; c[7][2] += a1.w * b0.z; c[7][3] += a1.w * b0.w;
            c[7][4] += a1.w * b1.x; c[7][5] += a1.w * b1.y; c[7][6] += a1.w * b1.z; c[7][7] += a1.w * b1.w;
        }
        __syncthreads();
    }

    // epilogue: bias + masked float4 stores (n-tiles are 16-aligned vs 912)
    const int nb = n0 + tx * 8;
    float4 bb0 = (nb + 3 < G3) ? *(const float4*)(bias + nb) : z4;
    float4 bb1 = (nb + 7 < G3) ? *(const float4*)(bias + nb + 4) : z4;
#pragma unroll
    for (int i = 0; i < 8; ++i) {
        const size_t m = (size_t)(m0 + ty * 8 + i);
        if (nb + 3 < G3) {
            float4 v = make_float4(c[i][0] + bb0.x, c[i][1] + bb0.y, c[i][2] + bb0.z, c[i][3] + bb0.w);
            *(float4*)(out + m * G3 + nb) = v;
        }
        if (nb + 7 < G3) {
            float4 v = make_float4(c[i][4] + bb1.x, c[i][5] + bb1.y, c[i][6] + bb1.z, c[i][7] + bb1.w);
            *(float4*)(out + m * G3 + nb + 4) = v;
        }
    }
}

// ---------------------------------------------------------------------------
// Phase 1b: decoder input-projection table
// ---------------------------------------------------------------------------
__global__ __launch_bounds__(256) void table_k(const float* __restrict__ emb,
                                               const float* __restrict__ Wih,
                                               const float* __restrict__ bih,
                                               float* __restrict__ tab)
{
    const int idx = blockIdx.x * 256 + threadIdx.x;  // 456*256 = 116736 = 128*912
    const int d = idx / G3;
    const int R = idx - d * G3;
    const float4* e4 = (const float4*)(emb + (size_t)d * HN);
    const float4* w4 = (const float4*)(Wih + (size_t)R * HN);
    float acc = 0.f;
#pragma unroll
    for (int j = 0; j < 76; ++j) {
        const float4 e = e4[j], w = w4[j];
        acc += e.x * w.x; acc += e.y * w.y; acc += e.z * w.z; acc += e.w * w.w;
    }
    tab[idx] = acc + bih[R];
}

// target_cal output
__global__ void tcal_k(const int* __restrict__ target, float* __restrict__ out)
{
    const int i = blockIdx.x * 256 + threadIdx.x;
    if (i < NB * LDEC) {
        const int b = i / LDEC;
        const int t = i - b * LDEC;
        out[OUT_O1 + i] = (float)target[b * 128 + t + 1];
    }
}

// Self-tagged poll (R5 form: single outstanding load — 3-deep variant regressed).
__device__ __forceinline__ unsigned poll_tag32(unsigned int* p, unsigned want, int* abortf)
{
    unsigned v; int g = 0;
    for (;;) {
        v = __hip_atomic_load(p, __ATOMIC_RELAXED, __HIP_MEMORY_SCOPE_AGENT);
        if ((v & 3u) == want) break;
        if ((++g & 255) == 0) {
            if (__hip_atomic_load(abortf, __ATOMIC_RELAXED, __HIP_MEMORY_SCOPE_AGENT) != 0) break;
            if (g > (1 << 19)) {  // deadlock valve: fail loudly, don't hang
                __hip_atomic_store(abortf, 1, __ATOMIC_RELAXED, __HIP_MEMORY_SCOPE_AGENT);
                break;
            }
        }
    }
    __asm__ volatile("" ::: "memory");
    return v;
}

// tagged 8B poll for argmax: wait until tag (high 32b, signed) >= want
__device__ __forceinline__ unsigned long long spin_tag(unsigned long long* p, int want, int* abortf)
{
    int g = 0;
    unsigned long long r;
    for (;;) {
        r = __hip_atomic_load(p, __ATOMIC_RELAXED, __HIP_MEMORY_SCOPE_AGENT);
        if ((int)(r >> 32) >= want) break;
        if ((++g & 255) == 0) {
            if (__hip_atomic_load(abortf, __ATOMIC_RELAXED, __HIP_MEMORY_SCOPE_AGENT) != 0) break;
            if (g > (1 << 19)) {
                __hip_atomic_store(abortf, 1, __ATOMIC_RELAXED, __HIP_MEMORY_SCOPE_AGENT);
                break;
            }
        }
    }
    __asm__ volatile("" ::: "memory");
    return r;
}

// ---------------------------------------------------------------------------
// Phase 2: persistent recurrence. 256 WGs x 512 threads, 1 WG/CU.
// (byte-identical to R7 — best-known config: 2 rows/thread GEMV, self-tagged
// h exchange, R5 decoder argmax.)
// ---------------------------------------------------------------------------
__global__ __launch_bounds__(512, 2) void rnn_persist(
    const float* __restrict__ gi,
    const float* __restrict__ encWhh, const float* __restrict__ encBhh,
    const float* __restrict__ decWhh, const float* __restrict__ decBhh,
    const float* __restrict__ tab,
    const float* __restrict__ linW, const float* __restrict__ linB,
    const int* __restrict__ target,
    unsigned int* hpk, unsigned long long* amax, int* abortf, float* out)
{
    const int w = blockIdx.x;
    const int b = w & 63;
    const int s = w >> 6;
    const int tid = threadIdx.x;

    __shared__ alignas(16) float hbuf[HN];
    __shared__ alignas(16) float part[4][RS];
    __shared__ alignas(16) float lpart[32][9];
    __shared__ float logit_s[32];
    __shared__ float amx_v[4];
    __shared__ int   amx_i[4];

    const bool comp = (tid < 456);
    const int ksq = tid / 114;          // k-group 0..3 (k-window [76*ksq, 76*ksq+76))
    const int lp  = tid - ksq * 114;    // row-pair index 0..113; rows lp and lp+114
    const int g0 = lp / US,        ul0 = lp - g0 * US;
    const int g1 = (lp + 114) / US, ul1 = (lp + 114) - g1 * US;
    const int Rrow0 = g0 * HN + s * US + ul0;
    const int Rrow1 = g1 * HN + s * US + ul1;
    const int u = s * US + tid;         // global hidden unit for tid<76
    const int cq = tid / US;            // slice owning element `tid` (tid<304)

    unsigned long long* amx = amax + b * 4;
    unsigned int* hpb = hpk + b * HN;   // parity stride = NB*HN

    // ---- encoder Whh: 2 rows x 76 k per thread (152 f32 in registers)
    float4 wreg0[19], wreg1[19];
    if (comp) {
        const float4* wp0 = (const float4*)(encWhh + (size_t)Rrow0 * HN + (size_t)ksq * US);
        const float4* wp1 = (const float4*)(encWhh + (size_t)Rrow1 * HN + (size_t)ksq * US);
#pragma unroll
        for (int j = 0; j < 19; ++j) { wreg0[j] = wp0[j]; wreg1[j] = wp1[j]; }
    }
    float b_r = 0.f, b_z = 0.f, b_n = 0.f;
    if (tid < US) { b_r = encBhh[u]; b_z = encBhh[HN + u]; b_n = encBhh[2 * HN + u]; }

    for (int i = tid; i < HN; i += 512) hbuf[i] = 0.f;   // h0 = 0
    __syncthreads();

    const float* gib = gi + (size_t)b * TSTEPS * G3;

    // ================= encoder: 1024 steps =================
    for (int t = 0; t < TSTEPS; ++t) {
        const int T = t + 1;                  // tag of the h this step produces
        float gr = 0.f, gz = 0.f, gn = 0.f;
        if (tid < US) {                       // gi load, hidden behind GEMV
            const float* gp = gib + (size_t)t * G3;
            gr = gp[u]; gz = gp[HN + u]; gn = gp[2 * HN + u];
        }
        if (comp) {                           // GEMV: 2 rows per thread, shared h reads
            const float4* hp = (const float4*)(hbuf + ksq * US);
            float acc0 = 0.f, acc1 = 0.f;
#pragma unroll
            for (int j = 0; j < 19; ++j) {
                const float4 h4 = hp[j];
                const float4 w0 = wreg0[j], w1 = wreg1[j];
                acc0 += w0.x * h4.x; acc0 += w0.y * h4.y; acc0 += w0.z * h4.z; acc0 += w0.w * h4.w;
                acc1 += w1.x * h4.x; acc1 += w1.y * h4.y; acc1 += w1.z * h4.z; acc1 += w1.w * h4.w;
            }
            part[ksq][lp] = acc0;
            part[ksq][lp + 114] = acc1;
        }
        __syncthreads();                      // barrier 1: part done, hbuf reads done
        if (tid < US) {
            const float ghr = part[0][tid] + part[1][tid] + part[2][tid] + part[3][tid] + b_r;
            const float ghz = part[0][US + tid] + part[1][US + tid] + part[2][US + tid] + part[3][US + tid] + b_z;
            const float ghn = part[0][2 * US + tid] + part[1][2 * US + tid] + part[2][2 * US + tid] + part[3][2 * US + tid] + b_n;
            const float r = 1.f / (1.f + expf(-(gr + ghr)));
            const float z = 1.f / (1.f + expf(-(gz + ghz)));
            const float n = tanhf(gn + r * ghn);
            const float hnew = (1.f - z) * n + z * hbuf[u];
            const unsigned hb = (__float_as_uint(hnew) & ~3u) | ((unsigned)T & 3u);
            hbuf[u] = __uint_as_float(hb);    // own slice, tagged (bit-identical everywhere)
            __hip_atomic_store(&hpb[(T & 1) * NB * HN + u], hb,
                               __ATOMIC_RELAXED, __HIP_MEMORY_SCOPE_AGENT);
        }
        if (tid < HN && cq != s) {            // fetch remote slices: data IS the flag
            const unsigned v = poll_tag32(&hpb[(T & 1) * NB * HN + tid],
                                          (unsigned)T & 3u, abortf);
            hbuf[tid] = __uint_as_float(v);
        }
        __syncthreads();                      // barrier 2: hbuf = h_{t+1}
    }

    // ---- decoder weights + biases
    if (comp) {
        const float4* wp0 = (const float4*)(decWhh + (size_t)Rrow0 * HN + (size_t)ksq * US);
        const float4* wp1 = (const float4*)(decWhh + (size_t)Rrow1 * HN + (size_t)ksq * US);
#pragma unroll
        for (int j = 0; j < 19; ++j) { wreg0[j] = wp0[j]; wreg1[j] = wp1[j]; }
    }
    if (tid < US) { b_r = decBhh[u]; b_z = decBhh[HN + u]; b_n = decBhh[2 * HN + u]; }
    int tok = target[b * 128];         // target[b,0,0]
    const int lrow = tid >> 3;         // logit row within slice (tid<256)
    const int lks = tid & 7;           // 8 k-slices of 38
    __syncthreads();

    // ================= decoder: 127 steps =================
    for (int t = 0; t < LDEC; ++t) {
        const int T = TSTEPS + 1 + t;         // h tag this step produces
        float gr = 0.f, gz = 0.f, gn = 0.f;
        if (tid < US) {
            const float* tp = tab + (size_t)tok * G3;
            gr = tp[u]; gz = tp[HN + u]; gn = tp[2 * HN + u];
        }
        if (comp) {
            const float4* hp = (const float4*)(hbuf + ksq * US);
            float acc0 = 0.f, acc1 = 0.f;
#pragma unroll
            for (int j = 0; j < 19; ++j) {
                const float4 h4 = hp[j];
                const float4 w0 = wreg0[j], w1 = wreg1[j];
                acc0 += w0.x * h4.x; acc0 += w0.y * h4.y; acc0 += w0.z * h4.z; acc0 += w0.w * h4.w;
                acc1 += w1.x * h4.x; acc1 += w1.y * h4.y; acc1 += w1.z * h4.z; acc1 += w1.w * h4.w;
            }
            part[ksq][lp] = acc0;
            part[ksq][lp + 114] = acc1;
        }
        __syncthreads();
        if (tid < US) {
            const float ghr = part[0][tid] + part[1][tid] + part[2][tid] + part[3][tid] + b_r;
            const float ghz = part[0][US + tid] + part[1][US + tid] + part[2][US + tid] + part[3][US + tid] + b_z;
            const float ghn = part[0][2 * US + tid] + part[1][2 * US + tid] + part[2][2 * US + tid] + part[3][2 * US + tid] + b_n;
            const float r = 1.f / (1.f + expf(-(gr + ghr)));
            const float z = 1.f / (1.f + expf(-(gz + ghz)));
            const float n = tanhf(gn + r * ghn);
            const float hnew = (1.f - z) * n + z * hbuf[u];
            const unsigned hb = (__float_as_uint(hnew) & ~3u) | ((unsigned)T & 3u);
            hbuf[u] = __uint_as_float(hb);
            __hip_atomic_store(&hpb[(T & 1) * NB * HN + u], hb,
                               __ATOMIC_RELAXED, __HIP_MEMORY_SCOPE_AGENT);
        }
        if (tid < HN && cq != s) {
            const unsigned v = poll_tag32(&hpb[(T & 1) * NB * HN + tid],
                                          (unsigned)T & 3u, abortf);
            hbuf[tid] = __uint_as_float(v);
        }
        __syncthreads();                      // hbuf = fresh h for logits

        // logits rows [32s, 32s+32)
        if (tid < 256) {
            const float2* wl = (const float2*)(linW + (size_t)(s * 32 + lrow) * HN + (size_t)lks * 38);
            const float2* hl = (const float2*)(hbuf + lks * 38);
            float a = 0.f;
#pragma unroll
            for (int j = 0; j < 19; ++j) { const float2 wv = wl[j], hv = hl[j]; a += wv.x * hv.x; a += wv.y * hv.y; }
            lpart[lrow][lks] = a;
        }
        __syncthreads();
        if (tid < 32) {
            const float lg = lpart[tid][0] + lpart[tid][1] + lpart[tid][2] + lpart[tid][3]
                           + lpart[tid][4] + lpart[tid][5] + lpart[tid][6] + lpart[tid][7]
                           + linB[s * 32 + tid];
            logit_s[tid] = lg;
            out[((size_t)b * LDEC + t) * DCLS + s * 32 + tid] = lg;   // softmax_cal
        }
        __syncthreads();
        if (tid == 0) {                       // publish local argmax: one tagged 8B store
            float bv = logit_s[0]; int bi = 0;
            for (int i = 1; i < 32; ++i) { const float v = logit_s[i]; if (v > bv) { bv = v; bi = i; } }
            const unsigned tagf = (unsigned)(((t + 1) << 8) | (s * 32 + bi));
            const unsigned long long pk = ((unsigned long long)tagf << 32) | (unsigned long long)__float_as_uint(bv);
            __hip_atomic_store(&amx[s], pk, __ATOMIC_RELAXED, __HIP_MEMORY_SCOPE_AGENT);
        }
        if (tid < 4) {                        // poll all 4 slices' argmaxes in parallel
            const unsigned long long r = spin_tag(&amx[tid], (t + 1) << 8, abortf);
            amx_v[tid] = __uint_as_float((unsigned)r);
            amx_i[tid] = (int)(r >> 32) & 255;
        }
        __syncthreads();
        {                                     // identical winner on all threads
            float gbv = amx_v[0]; int gbi = amx_i[0];
            if (amx_v[1] > gbv) { gbv = amx_v[1]; gbi = amx_i[1]; }
            if (amx_v[2] > gbv) { gbv = amx_v[2]; gbi = amx_i[2]; }
            if (amx_v[3] > gbv) { gbv = amx_v[3]; gbi = amx_i[3]; }
            tok = gbi;
            if (tid == 0 && s == 0) out[OUT_O2 + (size_t)b * LDEC + t] = (float)gbi;  // asr_outputs
        }
    }
}

// ---------------------------------------------------------------------------
extern "C" void kernel_launch(void* const* d_in, const int* in_sizes, int n_in,
                              void* d_out, int out_size, void* d_ws, size_t ws_size,
                              hipStream_t stream)
{
    (void)in_sizes; (void)n_in; (void)out_size;
    const float* x      = (const float*)d_in[0];
    const int*   target = (const int*)  d_in[1];
    const float* emb    = (const float*)d_in[2];
    const float* encWih = (const float*)d_in[3];
    const float* encWhh = (const float*)d_in[4];
    const float* encBih = (const float*)d_in[5];
    const float* encBhh = (const float*)d_in[6];
    const float* decWih = (const float*)d_in[7];
    const float* decWhh = (const float*)d_in[8];
    const float* decBih = (const float*)d_in[9];
    const float* decBhh = (const float*)d_in[10];
    const float* linW   = (const float*)d_in[11];
    const float* linB   = (const float*)d_in[12];
    float* out = (float*)d_out;
    char* ws = (char*)d_ws;

    if (ws_size < WS_NEED) return;  // insufficient scratch: fail visibly

    float*              gi   = (float*)(ws + OFF_GI);
    unsigned int*       hpk  = (unsigned int*)(ws + OFF_HP);
    unsigned long long* amax = (unsigned long long*)(ws + OFF_AM);
    int*                abrt = (int*)(ws + OFF_ABRT);
    float*              tab  = (float*)(ws + OFF_TAB);

    // zero tagged-h ping-pong (tag 0 = "unwritten"), argmax slots, abort flag
    hipMemsetAsync(ws + OFF_HP, 0, OFF_TAB - OFF_HP, stream);
    gi_gemm<<<dim3(512, 8), 256, 0, stream>>>(x, encWih, encBih, gi);
    table_k<<<456, 256, 0, stream>>>(emb, decWih, decBih, tab);
    tcal_k<<<32, 256, 0, stream>>>(target, out);
    rnn_persist<<<256, 512, 0, stream>>>(gi, encWhh, encBhh, decWhh, decBhh, tab,
                                         linW, linB, target, hpk, amax, abrt, out);
}